// Round 5
// baseline (325.236 us; speedup 1.0000x reference)
//
#include <hip/hip_runtime.h>
#include <hip/hip_bf16.h>
#include <math.h>

constexpr int DXc = 1024;
constexpr int DZc = 1024;
constexpr int LXc = 4096;
constexpr int LZc = 4096;
constexpr int DAc = 1024;   // DATTN
constexpr int DOc = 1024;   // DOUT

typedef __attribute__((ext_vector_type(8))) short bf16x8;
typedef __attribute__((ext_vector_type(4))) float f32x4;

__device__ __forceinline__ ushort f2bf(float f) {
    __hip_bfloat16 h = __float2bfloat16(f);
    return *reinterpret_cast<ushort*>(&h);
}
__device__ __forceinline__ float bf2f(ushort u) {
    return __builtin_bit_cast(float, (unsigned)u << 16);
}

enum BiasMode { BIAS_NONE, BIAS_M, BIAS_N };

// ---------------------------------------------------------------------------
// Core 128x128xK bf16 MFMA loop (both operands K-major): acc += A.B^T tile.
// 256 threads = 4 waves (2x2), each wave 64x64 via 4x4 MFMA 16x16x32.
// global_load_lds width=16 staging, contiguous lane-order LDS (no padding).
// ---------------------------------------------------------------------------
__device__ __forceinline__ void gemm_core(
    const ushort* __restrict__ A, const ushort* __restrict__ B,
    int K, int lda, int ldb, int m0, int n0, int kbase,
    ushort* As, ushort* Bs, f32x4 (*acc)[4])
{
    constexpr int BK = 32;
    const int tid = threadIdx.x;
    const int wv  = tid >> 6;
    const int wm  = (wv >> 1) * 64;
    const int wn  = (wv & 1) * 64;
    const int ln  = tid & 63;
    const int lrow = ln & 15;
    const int quad = ln >> 4;

    const int srow = tid >> 2;
    const int sseg = (tid & 3) * 8;
    const ushort* Ag = A + (size_t)(m0 + srow) * lda + sseg + kbase;
    const ushort* Bg = B + (size_t)(n0 + srow) * ldb + sseg + kbase;
    ushort* AsW = As + wv * 512;
    ushort* BsW = Bs + wv * 512;

    for (int k0 = 0; k0 < K; k0 += BK) {
        __syncthreads();
        __builtin_amdgcn_global_load_lds(
            (const __attribute__((address_space(1))) void*)(Ag + k0),
            (__attribute__((address_space(3))) void*)(AsW), 16, 0, 0);
        __builtin_amdgcn_global_load_lds(
            (const __attribute__((address_space(1))) void*)(Ag + (size_t)64 * lda + k0),
            (__attribute__((address_space(3))) void*)(AsW + 2048), 16, 0, 0);
        __builtin_amdgcn_global_load_lds(
            (const __attribute__((address_space(1))) void*)(Bg + k0),
            (__attribute__((address_space(3))) void*)(BsW), 16, 0, 0);
        __builtin_amdgcn_global_load_lds(
            (const __attribute__((address_space(1))) void*)(Bg + (size_t)64 * ldb + k0),
            (__attribute__((address_space(3))) void*)(BsW + 2048), 16, 0, 0);
        __syncthreads();

        bf16x8 af[4], bfr[4];
        #pragma unroll
        for (int t = 0; t < 4; ++t) {
            af[t]  = *reinterpret_cast<const bf16x8*>(&As[(wm + t * 16 + lrow) * BK + quad * 8]);
            bfr[t] = *reinterpret_cast<const bf16x8*>(&Bs[(wn + t * 16 + lrow) * BK + quad * 8]);
        }
        #pragma unroll
        for (int mi = 0; mi < 4; ++mi)
            #pragma unroll
            for (int nj = 0; nj < 4; ++nj)
                acc[mi][nj] = __builtin_amdgcn_mfma_f32_16x16x32_bf16(
                    af[mi], bfr[nj], acc[mi][nj], 0, 0, 0);
    }
}

// Epilogue: bias + bf16 store (projections)
template<BiasMode BMODE>
__device__ __forceinline__ void epi_bias_bf16(
    f32x4 (*acc)[4], const float* __restrict__ bias,
    ushort* __restrict__ C, int ldc, int m0, int n0)
{
    const int tid = threadIdx.x;
    const int wv  = tid >> 6;
    const int wm  = (wv >> 1) * 64;
    const int wn  = (wv & 1) * 64;
    const int lrow = tid & 15;
    const int quad = (tid & 63) >> 4;
    #pragma unroll
    for (int mi = 0; mi < 4; ++mi)
        #pragma unroll
        for (int r = 0; r < 4; ++r) {
            const int m = m0 + wm + mi * 16 + quad * 4 + r;
            const float bm = (BMODE == BIAS_M) ? bias[m] : 0.0f;
            #pragma unroll
            for (int nj = 0; nj < 4; ++nj) {
                const int n = n0 + wn + nj * 16 + lrow;
                const float v = acc[mi][nj][r] + ((BMODE == BIAS_N) ? bias[n] : bm);
                C[(size_t)m * ldc + n] = f2bf(v);
            }
        }
}

// ---------------------------------------------------------------------------
// Batched projection GEMM (768 blocks): q, k, v in one dispatch.
// ---------------------------------------------------------------------------
__global__ __launch_bounds__(256)
void proj_kernel(const ushort* __restrict__ XT, const ushort* __restrict__ ZT,
                 const ushort* __restrict__ Wqb, const ushort* __restrict__ Wkb,
                 const ushort* __restrict__ Wvb,
                 const float* __restrict__ bq, const float* __restrict__ bk,
                 const float* __restrict__ bv,
                 ushort* __restrict__ qT, ushort* __restrict__ kT,
                 ushort* __restrict__ vB)
{
    __shared__ __align__(16) ushort As[128 * 32];
    __shared__ __align__(16) ushort Bs[128 * 32];
    f32x4 acc[4][4] = {};
    int b = blockIdx.x;
    if (b < 256) {
        const int m0 = (b >> 3) * 128, n0 = (b & 7) * 128;
        gemm_core(XT, Wqb, DXc, DXc, DXc, m0, n0, 0, As, Bs, acc);
        epi_bias_bf16<BIAS_N>(acc, bq, qT, DAc, m0, n0);
    } else if (b < 512) {
        b -= 256;
        const int m0 = (b >> 3) * 128, n0 = (b & 7) * 128;
        gemm_core(ZT, Wkb, DZc, DZc, DZc, m0, n0, 0, As, Bs, acc);
        epi_bias_bf16<BIAS_N>(acc, bk, kT, DAc, m0, n0);
    } else {
        b -= 512;
        const int m0 = (b >> 5) * 128, n0 = (b & 31) * 128;
        gemm_core(Wvb, ZT, DZc, DZc, DZc, m0, n0, 0, As, Bs, acc);
        epi_bias_bf16<BIAS_M>(acc, bv, vB, LZc, m0, n0);
    }
}

// ---------------------------------------------------------------------------
// Score GEMM + fused mask/scale/exp + row-sum accumulation.
//   p[x,z] = mask ? exp(s/32 - 10) : 0   (bf16, unnormalized)
//   rowsum[x] += sum_z p  (bf16-rounded values, quad butterfly + atomicAdd)
// ---------------------------------------------------------------------------
__global__ __launch_bounds__(256)
void score_kernel(const ushort* __restrict__ qT, const ushort* __restrict__ kT,
                  ushort* __restrict__ sTb, const unsigned* __restrict__ bits,
                  float* __restrict__ rowsum)
{
    __shared__ __align__(16) ushort As[128 * 32];
    __shared__ __align__(16) ushort Bs[128 * 32];
    f32x4 acc[4][4] = {};
    const int b = blockIdx.x;
    const int m0 = (b >> 5) * 128, n0 = (b & 31) * 128;
    gemm_core(qT, kT, DAc, DAc, DAc, m0, n0, 0, As, Bs, acc);

    const int tid = threadIdx.x;
    const int wv  = tid >> 6;
    const int wm  = (wv >> 1) * 64;
    const int wn  = (wv & 1) * 64;
    const int lrow = tid & 15;
    const int quad = (tid & 63) >> 4;
    constexpr float scale = 1.0f / 32.0f;   // 1/sqrt(1024)
    const int wbase = (n0 + wn) >> 5;       // first of 2 mask words per row

    #pragma unroll
    for (int mi = 0; mi < 4; ++mi) {
        #pragma unroll
        for (int r = 0; r < 4; ++r) {
            const int m = m0 + wm + mi * 16 + quad * 4 + r;
            const unsigned w0 = bits[(size_t)m * 128 + wbase];
            const unsigned w1 = bits[(size_t)m * 128 + wbase + 1];
            float rsum = 0.0f;
            #pragma unroll
            for (int nj = 0; nj < 4; ++nj) {
                const int nn = nj * 16 + lrow;           // 0..63 in wave tile
                const unsigned wsel = (nn < 32) ? w0 : w1;
                const bool mk = (wsel >> (nn & 31)) & 1u;
                float p = mk ? __expf(acc[mi][nj][r] * scale - 10.0f) : 0.0f;
                const ushort pb = f2bf(p);
                sTb[(size_t)m * LZc + (n0 + wn + nn)] = pb;
                rsum += bf2f(pb);                        // sum what we stored
            }
            #pragma unroll
            for (int d = 1; d < 16; d <<= 1)
                rsum += __shfl_xor(rsum, d, 64);
            if (lrow == 0) atomicAdd(&rowsum[m], rsum);
        }
    }
}

// Out GEMM split-K=4: P[split][o][x] fp32 partials (unnormalized)
__global__ __launch_bounds__(256)
void out_kernel(const ushort* __restrict__ vB, const ushort* __restrict__ sTb,
                float* __restrict__ P)
{
    __shared__ __align__(16) ushort As[128 * 32];
    __shared__ __align__(16) ushort Bs[128 * 32];
    f32x4 acc[4][4] = {};
    const int m0 = blockIdx.y * 128, n0 = blockIdx.x * 128;
    gemm_core(vB, sTb, LZc / 4, LZc, LZc, m0, n0, blockIdx.z * (LZc / 4), As, Bs, acc);

    float* Cf = P + (size_t)blockIdx.z * DOc * LXc;
    const int tid = threadIdx.x;
    const int wv  = tid >> 6;
    const int wm  = (wv >> 1) * 64;
    const int wn  = (wv & 1) * 64;
    const int lrow = tid & 15;
    const int quad = (tid & 63) >> 4;
    #pragma unroll
    for (int mi = 0; mi < 4; ++mi)
        #pragma unroll
        for (int r = 0; r < 4; ++r) {
            const int m = m0 + wm + mi * 16 + quad * 4 + r;
            #pragma unroll
            for (int nj = 0; nj < 4; ++nj)
                Cf[(size_t)m * LXc + (n0 + wn + nj * 16 + lrow)] = acc[mi][nj][r];
        }
}

// ---------------------------------------------------------------------------
// Prep: X->XT bf16 transpose, Z->ZT, W converts, mask -> bitsT[x][z/32].
// ---------------------------------------------------------------------------
__global__ __launch_bounds__(256)
void prep_kernel(const float* __restrict__ X, const float* __restrict__ Z,
                 const float* __restrict__ Wq, const float* __restrict__ Wk,
                 const float* __restrict__ Wv, const int* __restrict__ mask,
                 ushort* __restrict__ XT, ushort* __restrict__ ZT,
                 ushort* __restrict__ Wqb, ushort* __restrict__ Wkb,
                 ushort* __restrict__ Wvb, unsigned* __restrict__ bits)
{
    __shared__ float tile[32][33];
    const int tid = threadIdx.x;
    int b = blockIdx.x;

    if (b < 8192) {
        const float* in  = (b < 4096) ? X : Z;
        ushort*      out = (b < 4096) ? XT : ZT;
        const int local = b & 4095;
        const int c0 = (local & 127) * 32, r0 = (local >> 7) * 32;
        const int tx = tid & 31, ty = tid >> 5;
        #pragma unroll
        for (int i = 0; i < 32; i += 8)
            tile[ty + i][tx] = in[(size_t)(r0 + ty + i) * LXc + c0 + tx];
        __syncthreads();
        #pragma unroll
        for (int i = 0; i < 32; i += 8)
            out[(size_t)(c0 + ty + i) * DXc + r0 + tx] = f2bf(tile[tx][ty + i]);
        return;
    }
    if (b < 11264) {
        b -= 8192;
        const float* in  = (b < 1024) ? Wq : (b < 2048) ? Wk : Wv;
        ushort*      out = (b < 1024) ? Wqb : (b < 2048) ? Wkb : Wvb;
        const size_t i = ((size_t)(b & 1023) * 256 + tid) * 4;
        float4 f = *reinterpret_cast<const float4*>(in + i);
        ushort4 u;
        u.x = f2bf(f.x); u.y = f2bf(f.y); u.z = f2bf(f.z); u.w = f2bf(f.w);
        *reinterpret_cast<ushort4*>(out + i) = u;
        return;
    }
    b -= 11264;
    const int xb = b & 15, zb = b >> 4;
    const int x  = xb * 256 + tid;
    const int z0 = zb * 32;
    unsigned w = 0;
    #pragma unroll 8
    for (int i = 0; i < 32; ++i)
        w |= (mask[(size_t)(z0 + i) * LXc + x] != 0 ? 1u : 0u) << i;
    bits[(size_t)x * (LZc / 32) + zb] = w;
}

// Sum 4 fp32 partials, divide by rowsum[x], write fp32 out (DO, LX)
__global__ __launch_bounds__(256)
void reduce_kernel(const float* __restrict__ P, const float* __restrict__ rowsum,
                   float* __restrict__ out)
{
    constexpr size_t total = (size_t)DOc * LXc;
    const size_t i = ((size_t)blockIdx.x * 256 + threadIdx.x) * 4;
    float4 s = *reinterpret_cast<const float4*>(P + i);
    #pragma unroll
    for (int p = 1; p < 4; ++p) {
        const float4 t = *reinterpret_cast<const float4*>(P + (size_t)p * total + i);
        s.x += t.x; s.y += t.y; s.z += t.z; s.w += t.w;
    }
    const float4 l = *reinterpret_cast<const float4*>(rowsum + (i & (LXc - 1)));
    s.x /= fmaxf(l.x, 1e-30f);
    s.y /= fmaxf(l.y, 1e-30f);
    s.z /= fmaxf(l.z, 1e-30f);
    s.w /= fmaxf(l.w, 1e-30f);
    *reinterpret_cast<float4*>(out + i) = s;
}

// ---------------------------------------------------------------------------
extern "C" void kernel_launch(void* const* d_in, const int* in_sizes, int n_in,
                              void* d_out, int out_size, void* d_ws, size_t ws_size,
                              hipStream_t stream)
{
    const float* X    = (const float*)d_in[0];
    const float* Z    = (const float*)d_in[1];
    const int*   mask = (const int*)  d_in[2];
    const float* Wq   = (const float*)d_in[3];
    const float* bq   = (const float*)d_in[4];
    const float* Wk   = (const float*)d_in[5];
    const float* bk   = (const float*)d_in[6];
    const float* Wv   = (const float*)d_in[7];
    const float* bv   = (const float*)d_in[8];
    float* out = (float*)d_out;

    // ws layout (~106.1 MB). P (64 MB at offset 0) overlays XT/ZT/W/qT/kT
    // (all dead once out_kernel runs).
    char* ws = (char*)d_ws;
    ushort*   XT     = (ushort*)(ws);                    // 8 MB
    ushort*   ZT     = (ushort*)(ws + ( 8ull << 20));    // 8 MB
    ushort*   Wqb    = (ushort*)(ws + (16ull << 20));    // 2 MB
    ushort*   Wkb    = (ushort*)(ws + (18ull << 20));    // 2 MB
    ushort*   Wvb    = (ushort*)(ws + (20ull << 20));    // 2 MB
    ushort*   qT     = (ushort*)(ws + (22ull << 20));    // 8 MB
    ushort*   kT     = (ushort*)(ws + (30ull << 20));    // 8 MB
    float*    P      = (float*) (ws);                    // 64 MB (overlay)
    ushort*   vB     = (ushort*)(ws + (64ull << 20));    // 8 MB
    ushort*   sTb    = (ushort*)(ws + (72ull << 20));    // 32 MB
    unsigned* bits   = (unsigned*)(ws + (104ull << 20)); // 2 MB
    float*    rowsum = (float*)  (ws + (106ull << 20));  // 16 KB

    prep_kernel<<<dim3(13312), 256, 0, stream>>>(X, Z, Wq, Wk, Wv, mask,
                                                 XT, ZT, Wqb, Wkb, Wvb, bits);
    proj_kernel<<<dim3(768), 256, 0, stream>>>(XT, ZT, Wqb, Wkb, Wvb,
                                               bq, bk, bv, qT, kT, vB);
    hipMemsetAsync(rowsum, 0, LXc * sizeof(float), stream);
    score_kernel<<<dim3(1024), 256, 0, stream>>>(qT, kT, sTb, bits, rowsum);
    out_kernel<<<dim3(32, 8, 4), 256, 0, stream>>>(vB, sTb, P);
    reduce_kernel<<<dim3(DOc * LXc / 1024), 256, 0, stream>>>(P, rowsum, out);
}